// Round 8
// baseline (579.058 us; speedup 1.0000x reference)
//
#include <hip/hip_runtime.h>
#include <math.h>

#define N_NODES 50000
#define E_EDGES 600000
#define IN_DIM  384
#define HID     128
#define HYP     256

#define SCAN_NB ((N_NODES + 255) / 256)   // 196
#define EMB_NB  ((N_NODES / 16) * 4)      // 12500: 16-row x 32-col tiles
#define DEG_NB  ((E_EDGES + 63) / 64)     // 9375

typedef __attribute__((ext_vector_type(8))) short bf16x8;
typedef __attribute__((ext_vector_type(4))) float f32x4;
typedef _Float16 f16x4 __attribute__((ext_vector_type(4)));
typedef _Float16 f16x8 __attribute__((ext_vector_type(8)));

__device__ __forceinline__ unsigned short f2bf(float f) {
    unsigned u = __builtin_bit_cast(unsigned, f);
    u = (u + 0x7FFFu + ((u >> 16) & 1u)) >> 16;
    return (unsigned short)u;
}

__device__ __forceinline__ bf16x8 cvt8(float4 p, float4 q) {
    bf16x8 a;
    a[0] = (short)f2bf(p.x); a[1] = (short)f2bf(p.y);
    a[2] = (short)f2bf(p.z); a[3] = (short)f2bf(p.w);
    a[4] = (short)f2bf(q.x); a[5] = (short)f2bf(q.y);
    a[6] = (short)f2bf(q.z); a[7] = (short)f2bf(q.w);
    return a;
}

// fp16x8 -> bf16x8 via float
__device__ __forceinline__ bf16x8 cvt8h(f16x8 h) {
    bf16x8 a;
#pragma unroll
    for (int i = 0; i < 8; ++i) a[i] = (short)f2bf((float)h[i]);
    return a;
}

// ---------------- graph preprocessing ----------------

// hierarchical scan, phase 1: per-block (256 elems) sum of deg -> bsum
__global__ __launch_bounds__(256) void k_scan1(const int* __restrict__ deg, int* __restrict__ bsum) {
    __shared__ int sh[256];
    int tid = threadIdx.x;
    int i = blockIdx.x * 256 + tid;
    sh[tid] = (i < N_NODES) ? deg[i] : 0;
    __syncthreads();
#pragma unroll
    for (int off = 128; off > 0; off >>= 1) {
        if (tid < off) sh[tid] += sh[tid + off];
        __syncthreads();
    }
    if (tid == 0) bsum[blockIdx.x] = sh[0];
}

// phase 2: single block scans the 196 block sums -> exclusive bbase
__global__ __launch_bounds__(256) void k_scan2(const int* __restrict__ bsum, int* __restrict__ bbase,
                                               int* __restrict__ row_start) {
    __shared__ int sh[256];
    int tid = threadIdx.x;
    int v = (tid < SCAN_NB) ? bsum[tid] : 0;
    sh[tid] = v;
    __syncthreads();
#pragma unroll
    for (int off = 1; off < 256; off <<= 1) {
        int t = (tid >= off) ? sh[tid - off] : 0;
        __syncthreads();
        sh[tid] += t;
        __syncthreads();
    }
    if (tid < SCAN_NB) bbase[tid] = sh[tid] - v;  // exclusive prefix of block sums
    if (tid == 0) row_start[N_NODES] = E_EDGES;
}

// phase 3: in-block exclusive scan + bbase -> row_start, dinv (coalesced)
__global__ __launch_bounds__(256) void k_scan3(const int* __restrict__ deg, const int* __restrict__ bbase,
                                               int* __restrict__ row_start, float* __restrict__ dinv) {
    __shared__ int sh[256];
    int tid = threadIdx.x;
    int i = blockIdx.x * 256 + tid;
    int d = (i < N_NODES) ? deg[i] : 0;
    sh[tid] = d;
    __syncthreads();
#pragma unroll
    for (int off = 1; off < 256; off <<= 1) {
        int t = (tid >= off) ? sh[tid - off] : 0;
        __syncthreads();
        sh[tid] += t;
        __syncthreads();
    }
    if (i < N_NODES) {
        row_start[i] = sh[tid] - d + bbase[blockIdx.x];
        dinv[i] = (d > 0) ? rsqrtf((float)d) : 0.0f;
    }
}

// fill CSR with interleaved (src, weight) pairs -> one 8B load per edge in k_prop
__global__ void k_fill(const int* __restrict__ src, const int* __restrict__ dst,
                       const int* __restrict__ row_start, int* __restrict__ cnt,
                       const float* __restrict__ dinv, int2* __restrict__ csr_sw) {
    int i = blockIdx.x * blockDim.x + threadIdx.x;
    if (i < E_EDGES) {
        int d = dst[i], s = src[i];
        int pos = row_start[d] + atomicAdd(&cnt[d], 1);
        csr_sw[pos] = make_int2(s, __float_as_int(dinv[s] * dinv[d]));
    }
}

// ---------------- fused weight transpose + fp32->bf16 (1 launch) ----------------

__global__ __launch_bounds__(256) void k_cvt_all(const float* __restrict__ wf, const float* __restrict__ wh,
                                                 const float* __restrict__ wv, const float* __restrict__ wt,
                                                 unsigned short* __restrict__ wfT, unsigned short* __restrict__ whT,
                                                 unsigned short* __restrict__ wvT, unsigned short* __restrict__ wtT) {
    int i = blockIdx.x * 256 + threadIdx.x;
    if (i < 49152) {
        int r = i >> 7, c = i & 127;                       // in [384][128]
        wfT[(size_t)c * IN_DIM + r] = f2bf(wf[i]);
    } else if (i < 49152 + 32768) {
        int j = i - 49152;
        int r = j >> 8, c = j & 255;                       // in [128][256]
        whT[(size_t)c * HID + r] = f2bf(wh[j]);
    } else if (i < 49152 + 32768 + 16384) {
        int j = i - 81920;
        int r = j >> 7, c = j & 127;                       // in [128][128]
        wvT[(size_t)c * HID + r] = f2bf(wv[j]);
    } else {
        int j = i - 98304;
        int r = j >> 7, c = j & 127;
        wtT[(size_t)c * HID + r] = f2bf(wt[j]);
    }
}

// ---------------- FUSED: x_emb GEMM (blocks < EMB_NB) || degree count (blocks >= EMB_NB) ----------
// Round-8: VGPR_Count=60 proved the old "preload 12 float4" never stayed in flight (needs 48
// regs + 32 acc) — compiler pipelined ~2-deep; with ~12 resident waves/CU that's starvation-level
// MLP, matching 900 GB/s effective and all-pipes-idle. New shape: 1 wave / 16x32 output tile,
// no LDS, no barrier, ~45 VGPR -> 8 waves/SIMD schedulable; 12500 emb blocks give ~85 waves/CU
// of work. Col-tiles of the same rows are adjacent block IDs (b&3) -> x re-reads are L2/L3 hits.

__global__ __launch_bounds__(64) void k_embdeg(const float* __restrict__ x, const unsigned short* __restrict__ wfT,
                                               const float* __restrict__ bf_, _Float16* __restrict__ x_embh,
                                               const int* __restrict__ dst, int* __restrict__ deg) {
    int b = blockIdx.x;
    int lane = threadIdx.x;
    if (b >= EMB_NB) {
        int i = (b - EMB_NB) * 64 + lane;
        if (i < E_EDGES) atomicAdd(&deg[dst[i]], 1);
        return;
    }
    int ct = b & 3;            // col tile (low bits -> same-row tiles dispatch together)
    int m0 = (b >> 2) * 16;
    int c0 = ct * 32;
    int l16 = lane & 15, quad = lane >> 4;
    const float* xrow = x + (size_t)(m0 + l16) * IN_DIM + quad * 8;
    const unsigned short* wp0 = wfT + (size_t)(c0 + l16) * IN_DIM + quad * 8;
    const unsigned short* wp1 = wp0 + (size_t)16 * IN_DIM;
    f32x4 acc0 = (f32x4){0.f, 0.f, 0.f, 0.f};
    f32x4 acc1 = (f32x4){0.f, 0.f, 0.f, 0.f};
#pragma unroll
    for (int kt = 0; kt < 12; ++kt) {
        float4 p = *reinterpret_cast<const float4*>(xrow + kt * 32);
        float4 q = *reinterpret_cast<const float4*>(xrow + kt * 32 + 4);
        bf16x8 a = cvt8(p, q);
        bf16x8 b0 = *reinterpret_cast<const bf16x8*>(wp0 + kt * 32);
        bf16x8 b1 = *reinterpret_cast<const bf16x8*>(wp1 + kt * 32);
        acc0 = __builtin_amdgcn_mfma_f32_16x16x32_bf16(a, b0, acc0, 0, 0, 0);
        acc1 = __builtin_amdgcn_mfma_f32_16x16x32_bf16(a, b1, acc1, 0, 0, 0);
    }
    float bias0 = bf_[c0 + l16];
    float bias1 = bf_[c0 + 16 + l16];
#pragma unroll
    for (int r = 0; r < 4; ++r) {
        size_t row = (size_t)(m0 + quad * 4 + r);
        x_embh[row * HID + c0 + l16]      = (_Float16)(acc0[r] + bias0);
        x_embh[row * HID + c0 + 16 + l16] = (_Float16)(acc1[r] + bias1);
    }
}

// ---------------- one LightGCN layer: fp16 gather, fp32 accumulate ----------------
// INIT: accb = (float)curh[o] + a   (curh == x_embh)
// else: accb += a.  LAST skips dead nxt store.

__device__ __forceinline__ void fma4h(float4& a, const f16x4 v, float s) {
    a.x = fmaf((float)v.x, s, a.x);
    a.y = fmaf((float)v.y, s, a.y);
    a.z = fmaf((float)v.z, s, a.z);
    a.w = fmaf((float)v.w, s, a.w);
}

template <int INIT, int LAST>
__global__ __launch_bounds__(256) void k_prop(const _Float16* __restrict__ curh, _Float16* __restrict__ nxth,
                                              float* __restrict__ accb,
                                              const int* __restrict__ row_start,
                                              const int2* __restrict__ csr_sw) {
    int tid = threadIdx.x;
    int n = blockIdx.x * 8 + (tid >> 5);
    int c4 = (tid & 31) * 4;
    int s = row_start[n];
    int e = row_start[n + 1];
    float4 a[8];
#pragma unroll
    for (int k = 0; k < 8; ++k) a[k] = (float4){0.f, 0.f, 0.f, 0.f};
    for (int i = s; i < e; i += 8) {
        int2 pk[8];
        float wk[8];
#pragma unroll
        for (int k = 0; k < 8; ++k) {
            int j = i + k;
            pk[k] = csr_sw[(j < e) ? j : s];
            wk[k] = (j < e) ? __int_as_float(pk[k].y) : 0.0f;
        }
        f16x4 v[8];
#pragma unroll
        for (int k = 0; k < 8; ++k)
            v[k] = *reinterpret_cast<const f16x4*>(&curh[(size_t)pk[k].x * HID + c4]);
#pragma unroll
        for (int k = 0; k < 8; ++k) fma4h(a[k], v[k], wk[k]);
    }
    a[0].x += a[1].x; a[0].y += a[1].y; a[0].z += a[1].z; a[0].w += a[1].w;
    a[2].x += a[3].x; a[2].y += a[3].y; a[2].z += a[3].z; a[2].w += a[3].w;
    a[4].x += a[5].x; a[4].y += a[5].y; a[4].z += a[5].z; a[4].w += a[5].w;
    a[6].x += a[7].x; a[6].y += a[7].y; a[6].z += a[7].z; a[6].w += a[7].w;
    a[0].x += a[2].x; a[0].y += a[2].y; a[0].z += a[2].z; a[0].w += a[2].w;
    a[4].x += a[6].x; a[4].y += a[6].y; a[4].z += a[6].z; a[4].w += a[6].w;
    a[0].x += a[4].x; a[0].y += a[4].y; a[0].z += a[4].z; a[0].w += a[4].w;
    size_t o = (size_t)n * HID + c4;
    if (!LAST) {
        f16x4 oh;
        oh.x = (_Float16)a[0].x; oh.y = (_Float16)a[0].y;
        oh.z = (_Float16)a[0].z; oh.w = (_Float16)a[0].w;
        *reinterpret_cast<f16x4*>(&nxth[o]) = oh;
    }
    float4 ac;
    if (INIT) {
        f16x4 bh = *reinterpret_cast<const f16x4*>(&curh[o]);
        ac = make_float4((float)bh.x, (float)bh.y, (float)bh.z, (float)bh.w);
    } else {
        ac = *reinterpret_cast<const float4*>(&accb[o]);
    }
    ac.x += a[0].x; ac.y += a[0].y; ac.z += a[0].z; ac.w += a[0].w;
    *reinterpret_cast<float4*>(&accb[o]) = ac;
}

// ---------------- Hm = softmax((x_emb @ w_hyper + g)/tau) : MFMA, fp16 in/out ----------------

__global__ __launch_bounds__(64) void k_soft(const _Float16* __restrict__ x_embh,
                                             const unsigned short* __restrict__ whT,
                                             const float* __restrict__ gu, _Float16* __restrict__ Hmh) {
    int lane = threadIdx.x & 63;
    int l16 = lane & 15, quad = lane >> 4;
    int m0 = blockIdx.x * 16;
    const _Float16* xrow = x_embh + (size_t)(m0 + l16) * HID + quad * 8;
    f32x4 acc[16];
#pragma unroll
    for (int nt = 0; nt < 16; ++nt) acc[nt] = (f32x4){0.f, 0.f, 0.f, 0.f};
#pragma unroll
    for (int kt = 0; kt < HID / 32; ++kt) {
        f16x8 h = *reinterpret_cast<const f16x8*>(xrow + kt * 32);
        bf16x8 a = cvt8h(h);
#pragma unroll
        for (int nt = 0; nt < 16; ++nt) {
            bf16x8 b = *reinterpret_cast<const bf16x8*>(&whT[(size_t)(nt * 16 + l16) * HID + kt * 32 + quad * 8]);
            acc[nt] = __builtin_amdgcn_mfma_f32_16x16x32_bf16(a, b, acc[nt], 0, 0, 0);
        }
    }
    // gumbel + 1/tau
#pragma unroll
    for (int nt = 0; nt < 16; ++nt) {
        int col = nt * 16 + l16;
#pragma unroll
        for (int r = 0; r < 4; ++r) {
            int row = m0 + quad * 4 + r;
            float u = gu[(size_t)row * HYP + col];
            float g = -logf(-logf(u + 1e-10f) + 1e-10f);
            acc[nt][r] = (acc[nt][r] + g) * 2.0f;
        }
    }
    // row max / sum over cols: per-lane over nt, then shfl over lane&15 group
    float mx[4] = {-3.4e38f, -3.4e38f, -3.4e38f, -3.4e38f};
#pragma unroll
    for (int nt = 0; nt < 16; ++nt)
#pragma unroll
        for (int r = 0; r < 4; ++r) mx[r] = fmaxf(mx[r], acc[nt][r]);
#pragma unroll
    for (int r = 0; r < 4; ++r) {
        mx[r] = fmaxf(mx[r], __shfl_xor(mx[r], 1));
        mx[r] = fmaxf(mx[r], __shfl_xor(mx[r], 2));
        mx[r] = fmaxf(mx[r], __shfl_xor(mx[r], 4));
        mx[r] = fmaxf(mx[r], __shfl_xor(mx[r], 8));
    }
    float sm[4] = {0.f, 0.f, 0.f, 0.f};
#pragma unroll
    for (int nt = 0; nt < 16; ++nt)
#pragma unroll
        for (int r = 0; r < 4; ++r) {
            float e = __expf(acc[nt][r] - mx[r]);
            acc[nt][r] = e;
            sm[r] += e;
        }
#pragma unroll
    for (int r = 0; r < 4; ++r) {
        sm[r] += __shfl_xor(sm[r], 1);
        sm[r] += __shfl_xor(sm[r], 2);
        sm[r] += __shfl_xor(sm[r], 4);
        sm[r] += __shfl_xor(sm[r], 8);
        sm[r] = 1.0f / sm[r];
    }
#pragma unroll
    for (int nt = 0; nt < 16; ++nt) {
        int col = nt * 16 + l16;
#pragma unroll
        for (int r = 0; r < 4; ++r)
            Hmh[(size_t)(m0 + quad * 4 + r) * HYP + col] = (_Float16)(acc[nt][r] * sm[r]);
    }
}

// ---------------- lat = Hm^T @ x_emb : fp16 reads, fp32 outer product, split-K, ATOMIC-FREE ----

#define LAT_KC 384

__global__ __launch_bounds__(256) void k_lat(const _Float16* __restrict__ Hmh, const _Float16* __restrict__ x_embh,
                                             float* __restrict__ part) {
    int htile = blockIdx.x & 1;
    int kc = blockIdx.x >> 1;
    const int chunk = (N_NODES + LAT_KC - 1) / LAT_KC;  // 131
    int start = kc * chunk;
    int end = min(N_NODES, start + chunk);
    int nn = end - start;  // may be <= 0 for the last couple of chunks
    int tid = threadIdx.x;
    int lh = (tid & 15) * 8;               // 8 consecutive h (within half) per thread
    int d = (tid >> 4) * 8;                // 8 consecutive d per thread
    const _Float16* __restrict__ hp = Hmh + (size_t)start * HYP + htile * 128 + lh;
    const _Float16* __restrict__ xp = x_embh + (size_t)start * HID + d;
    float acc[8][8];
#pragma unroll
    for (int i = 0; i < 8; ++i)
#pragma unroll
        for (int j = 0; j < 8; ++j) acc[i][j] = 0.f;
#pragma unroll 2
    for (int n = 0; n < nn; ++n) {
        f16x8 ah = *reinterpret_cast<const f16x8*>(hp);
        f16x8 bh = *reinterpret_cast<const f16x8*>(xp);
        float av[8], bv[8];
#pragma unroll
        for (int i = 0; i < 8; ++i) { av[i] = (float)ah[i]; bv[i] = (float)bh[i]; }
#pragma unroll
        for (int i = 0; i < 8; ++i)
#pragma unroll
            for (int j = 0; j < 8; ++j) acc[i][j] = fmaf(av[i], bv[j], acc[i][j]);
        hp += HYP;
        xp += HID;
    }
    float* __restrict__ pp = part + (size_t)blockIdx.x * (128 * 128) + (size_t)lh * 128 + d;
#pragma unroll
    for (int i = 0; i < 8; ++i) {
        float4 v0 = {acc[i][0], acc[i][1], acc[i][2], acc[i][3]};
        float4 v1 = {acc[i][4], acc[i][5], acc[i][6], acc[i][7]};
        *reinterpret_cast<float4*>(pp + i * 128) = v0;
        *reinterpret_cast<float4*>(pp + i * 128 + 4) = v1;
    }
}

// ---------------- reduce split-K partials -> latT (bf16, transposed) directly ----------------

__global__ __launch_bounds__(256) void k_lat_red(const float* __restrict__ part, unsigned short* __restrict__ latT) {
    int idx = blockIdx.x * 256 + threadIdx.x;  // [0, 32768)
    int d = idx & 127;
    int h = idx >> 7;
    int htile = h >> 7;
    int lh = h & 127;
    const float* __restrict__ p0 = part + (size_t)htile * (128 * 128) + (size_t)lh * 128 + d;
    const size_t kstride = (size_t)2 * 128 * 128;  // consecutive kc
    float s0 = 0.f, s1 = 0.f, s2 = 0.f, s3 = 0.f;
#pragma unroll 4
    for (int k = 0; k < LAT_KC; k += 4) {
        s0 += p0[(size_t)k * kstride];
        s1 += p0[(size_t)(k + 1) * kstride];
        s2 += p0[(size_t)(k + 2) * kstride];
        s3 += p0[(size_t)(k + 3) * kstride];
    }
    latT[(size_t)d * HYP + h] = f2bf((s0 + s1) + (s2 + s3));
}

// ---------------- tail: hyper = Hm @ lat; norm; final; two head GEMMs — MFMA, 1 wave/block ----------------

__global__ __launch_bounds__(64) void k_tail(const _Float16* __restrict__ Hmh, const unsigned short* __restrict__ latT,
                                             const float* __restrict__ accb,
                                             const unsigned short* __restrict__ wvT, const float* __restrict__ bv,
                                             const unsigned short* __restrict__ wtT, const float* __restrict__ bt,
                                             float* __restrict__ out_final, float* __restrict__ out_vis,
                                             float* __restrict__ out_txt) {
    __shared__ unsigned short fl[16 * HID];  // final tile, bf16, 4 KB
    int lane = threadIdx.x & 63;
    int l16 = lane & 15, quad = lane >> 4;
    int m0 = blockIdx.x * 16;
    const _Float16* hrow = Hmh + (size_t)(m0 + l16) * HYP + quad * 8;
    f32x4 acc[8];
#pragma unroll
    for (int nt = 0; nt < 8; ++nt) acc[nt] = (f32x4){0.f, 0.f, 0.f, 0.f};
#pragma unroll
    for (int kt = 0; kt < HYP / 32; ++kt) {
        f16x8 h = *reinterpret_cast<const f16x8*>(hrow + kt * 32);
        bf16x8 a = cvt8h(h);
#pragma unroll
        for (int nt = 0; nt < 8; ++nt) {
            bf16x8 b = *reinterpret_cast<const bf16x8*>(&latT[(size_t)(nt * 16 + l16) * HYP + kt * 32 + quad * 8]);
            acc[nt] = __builtin_amdgcn_mfma_f32_16x16x32_bf16(a, b, acc[nt], 0, 0, 0);
        }
    }
    // per-row L2 norm: rows = m0 + quad*4 + r; reduce over cols = nt x (lane&15)
    float ss[4] = {0.f, 0.f, 0.f, 0.f};
#pragma unroll
    for (int nt = 0; nt < 8; ++nt)
#pragma unroll
        for (int r = 0; r < 4; ++r) ss[r] = fmaf(acc[nt][r], acc[nt][r], ss[r]);
#pragma unroll
    for (int r = 0; r < 4; ++r) {
        ss[r] += __shfl_xor(ss[r], 1);
        ss[r] += __shfl_xor(ss[r], 2);
        ss[r] += __shfl_xor(ss[r], 4);
        ss[r] += __shfl_xor(ss[r], 8);
        ss[r] = 1.0f / fmaxf(sqrtf(ss[r]), 1e-12f);
    }
    // final = accb/4 + 0.1 * normalized; store + stage bf16 tile for head GEMMs
#pragma unroll
    for (int nt = 0; nt < 8; ++nt) {
        int col = nt * 16 + l16;
#pragma unroll
        for (int r = 0; r < 4; ++r) {
            int lrow = quad * 4 + r;
            size_t o = (size_t)(m0 + lrow) * HID + col;
            float f = accb[o] * 0.25f + 0.1f * (acc[nt][r] * ss[r]);
            out_final[o] = f;
            fl[lrow * HID + col] = f2bf(f);
        }
    }
    __syncthreads();
    // heads: A = final tile (LDS), B = wvT / wtT
    f32x4 av[8], at4[8];
#pragma unroll
    for (int nt = 0; nt < 8; ++nt) {
        av[nt] = (f32x4){0.f, 0.f, 0.f, 0.f};
        at4[nt] = (f32x4){0.f, 0.f, 0.f, 0.f};
    }
#pragma unroll
    for (int kt = 0; kt < HID / 32; ++kt) {
        bf16x8 a = *reinterpret_cast<const bf16x8*>(&fl[l16 * HID + kt * 32 + quad * 8]);
#pragma unroll
        for (int nt = 0; nt < 8; ++nt) {
            bf16x8 b1 = *reinterpret_cast<const bf16x8*>(&wvT[(size_t)(nt * 16 + l16) * HID + kt * 32 + quad * 8]);
            bf16x8 b2 = *reinterpret_cast<const bf16x8*>(&wtT[(size_t)(nt * 16 + l16) * HID + kt * 32 + quad * 8]);
            av[nt] = __builtin_amdgcn_mfma_f32_16x16x32_bf16(a, b1, av[nt], 0, 0, 0);
            at4[nt] = __builtin_amdgcn_mfma_f32_16x16x32_bf16(a, b2, at4[nt], 0, 0, 0);
        }
    }
#pragma unroll
    for (int nt = 0; nt < 8; ++nt) {
        int col = nt * 16 + l16;
        float b1 = bv[col], b2 = bt[col];
#pragma unroll
        for (int r = 0; r < 4; ++r) {
            size_t o = (size_t)(m0 + quad * 4 + r) * HID + col;
            out_vis[o] = fmaxf(av[nt][r] + b1, 0.0f);
            out_txt[o] = fmaxf(at4[nt][r] + b2, 0.0f);
        }
    }
}

// ---------------- launch ----------------

extern "C" void kernel_launch(void* const* d_in, const int* in_sizes, int n_in,
                              void* d_out, int out_size, void* d_ws, size_t ws_size,
                              hipStream_t stream) {
    const float* x      = (const float*)d_in[0];
    const int*   ei     = (const int*)d_in[1];
    const float* gu     = (const float*)d_in[2];
    const float* w_feat = (const float*)d_in[3];
    const float* b_feat = (const float*)d_in[4];
    const float* w_hyp  = (const float*)d_in[5];
    const float* w_vis  = (const float*)d_in[6];
    const float* b_vis  = (const float*)d_in[7];
    const float* w_txt  = (const float*)d_in[8];
    const float* b_txt  = (const float*)d_in[9];
    float* out = (float*)d_out;

    const int* srcv = ei;
    const int* dstv = ei + E_EDGES;

    // 64B-aligned workspace carve
    char* p = (char*)d_ws;
    auto carve = [&p](size_t bytes) {
        char* r = p;
        p += (bytes + 63) & ~(size_t)63;
        return r;
    };
    int*      deg     = (int*)carve((size_t)N_NODES * 4);
    int*      cnt     = (int*)carve((size_t)N_NODES * 4);
    int*      rs      = (int*)carve((size_t)(N_NODES + 1) * 4);
    float*    dinv    = (float*)carve((size_t)N_NODES * 4);
    int2*     csr_sw  = (int2*)carve((size_t)E_EDGES * 8);
    _Float16* x_embh  = (_Float16*)carve((size_t)N_NODES * HID * 2);
    float*    bufA    = (float*)carve((size_t)N_NODES * HID * 4);   // fp16 layer bufs + latPart overlay
    float*    bufB    = (float*)carve((size_t)N_NODES * HID * 4);
    float*    accb    = (float*)carve((size_t)N_NODES * HID * 4);
    _Float16* Hmh     = (_Float16*)carve((size_t)N_NODES * HYP * 2);
    unsigned short* wfT  = (unsigned short*)carve((size_t)HID * IN_DIM * 2);
    unsigned short* whT  = (unsigned short*)carve((size_t)HYP * HID * 2);
    unsigned short* wvT  = (unsigned short*)carve((size_t)HID * HID * 2);
    unsigned short* wtT  = (unsigned short*)carve((size_t)HID * HID * 2);
    unsigned short* latT = (unsigned short*)carve((size_t)HID * HYP * 2);
    int*      bsum    = (int*)carve((size_t)SCAN_NB * 4);
    int*      bbase   = (int*)carve((size_t)SCAN_NB * 4);

    // fp16 layer buffers live in the fp32-sized bufA/bufB slots; latPart (768 x 64KB
    // = 50.33 MB split-K partials) overlays bufA+bufB, which are dead after the prop chain.
    _Float16* bufAh = (_Float16*)bufA;
    _Float16* bufBh = (_Float16*)bufB;
    float* latPart = bufA;

    // zero: deg + cnt (first two carves, contiguous)
    (void)hipMemsetAsync(d_ws, 0, (size_t)2 * N_NODES * 4 + 128, stream);

    k_cvt_all<<<448, 256, 0, stream>>>(w_feat, w_hyp, w_vis, w_txt, wfT, whT, wvT, wtT);

    // fused: x_emb GEMM (1-wave 16x32 tiles) || degree count
    k_embdeg<<<EMB_NB + DEG_NB, 64, 0, stream>>>(x, wfT, b_feat, x_embh, dstv, deg);

    k_scan1<<<SCAN_NB, 256, 0, stream>>>(deg, bsum);
    k_scan2<<<1, 256, 0, stream>>>(bsum, bbase, rs);
    k_scan3<<<SCAN_NB, 256, 0, stream>>>(deg, bbase, rs, dinv);
    k_fill<<<(E_EDGES + 255) / 256, 256, 0, stream>>>(srcv, dstv, rs, cnt, dinv, csr_sw);

    k_prop<1, 0><<<N_NODES / 8, 256, 0, stream>>>(x_embh, bufAh, accb, rs, csr_sw);
    k_prop<0, 0><<<N_NODES / 8, 256, 0, stream>>>(bufAh, bufBh, accb, rs, csr_sw);
    k_prop<0, 1><<<N_NODES / 8, 256, 0, stream>>>(bufBh, bufAh, accb, rs, csr_sw);
    k_soft<<<N_NODES / 16, 64, 0, stream>>>(x_embh, whT, gu, Hmh);
    k_lat<<<2 * LAT_KC, 256, 0, stream>>>(Hmh, x_embh, latPart);
    k_lat_red<<<(HYP * HID) / 256, 256, 0, stream>>>(latPart, latT);
    k_tail<<<N_NODES / 16, 64, 0, stream>>>(Hmh, latT, accb, wvT, b_vis, wtT, b_txt,
                                            out, out + (size_t)N_NODES * HID, out + (size_t)2 * N_NODES * HID);
}

// Round 9
// 560.279 us; speedup vs baseline: 1.0335x; 1.0335x over previous
//
#include <hip/hip_runtime.h>
#include <math.h>

#define N_NODES 50000
#define E_EDGES 600000
#define IN_DIM  384
#define HID     128
#define HYP     256

#define SCAN_NB ((N_NODES + 255) / 256)   // 196
#define EMB_NB  (N_NODES / 16)            // 3125: one 16-row x 128-col tile per 4-wave block
#define DEG_NB  ((E_EDGES + 255) / 256)   // 2344

#define XS_STRIDE 392                     // 384 + 8 bf16 pad: 784B rows -> 16B-aligned, 2-way-free banks

typedef __attribute__((ext_vector_type(8))) short bf16x8;
typedef __attribute__((ext_vector_type(4))) float f32x4;
typedef _Float16 f16x4 __attribute__((ext_vector_type(4)));
typedef _Float16 f16x8 __attribute__((ext_vector_type(8)));

__device__ __forceinline__ unsigned short f2bf(float f) {
    unsigned u = __builtin_bit_cast(unsigned, f);
    u = (u + 0x7FFFu + ((u >> 16) & 1u)) >> 16;
    return (unsigned short)u;
}

__device__ __forceinline__ bf16x8 cvt8(float4 p, float4 q) {
    bf16x8 a;
    a[0] = (short)f2bf(p.x); a[1] = (short)f2bf(p.y);
    a[2] = (short)f2bf(p.z); a[3] = (short)f2bf(p.w);
    a[4] = (short)f2bf(q.x); a[5] = (short)f2bf(q.y);
    a[6] = (short)f2bf(q.z); a[7] = (short)f2bf(q.w);
    return a;
}

// fp16x8 -> bf16x8 via float
__device__ __forceinline__ bf16x8 cvt8h(f16x8 h) {
    bf16x8 a;
#pragma unroll
    for (int i = 0; i < 8; ++i) a[i] = (short)f2bf((float)h[i]);
    return a;
}

// ---------------- graph preprocessing ----------------

// hierarchical scan, phase 1: per-block (256 elems) sum of deg -> bsum
__global__ __launch_bounds__(256) void k_scan1(const int* __restrict__ deg, int* __restrict__ bsum) {
    __shared__ int sh[256];
    int tid = threadIdx.x;
    int i = blockIdx.x * 256 + tid;
    sh[tid] = (i < N_NODES) ? deg[i] : 0;
    __syncthreads();
#pragma unroll
    for (int off = 128; off > 0; off >>= 1) {
        if (tid < off) sh[tid] += sh[tid + off];
        __syncthreads();
    }
    if (tid == 0) bsum[blockIdx.x] = sh[0];
}

// phase 2: single block scans the 196 block sums -> exclusive bbase
__global__ __launch_bounds__(256) void k_scan2(const int* __restrict__ bsum, int* __restrict__ bbase,
                                               int* __restrict__ row_start) {
    __shared__ int sh[256];
    int tid = threadIdx.x;
    int v = (tid < SCAN_NB) ? bsum[tid] : 0;
    sh[tid] = v;
    __syncthreads();
#pragma unroll
    for (int off = 1; off < 256; off <<= 1) {
        int t = (tid >= off) ? sh[tid - off] : 0;
        __syncthreads();
        sh[tid] += t;
        __syncthreads();
    }
    if (tid < SCAN_NB) bbase[tid] = sh[tid] - v;  // exclusive prefix of block sums
    if (tid == 0) row_start[N_NODES] = E_EDGES;
}

// phase 3: in-block exclusive scan + bbase -> row_start, dinv (coalesced)
__global__ __launch_bounds__(256) void k_scan3(const int* __restrict__ deg, const int* __restrict__ bbase,
                                               int* __restrict__ row_start, float* __restrict__ dinv) {
    __shared__ int sh[256];
    int tid = threadIdx.x;
    int i = blockIdx.x * 256 + tid;
    int d = (i < N_NODES) ? deg[i] : 0;
    sh[tid] = d;
    __syncthreads();
#pragma unroll
    for (int off = 1; off < 256; off <<= 1) {
        int t = (tid >= off) ? sh[tid - off] : 0;
        __syncthreads();
        sh[tid] += t;
        __syncthreads();
    }
    if (i < N_NODES) {
        row_start[i] = sh[tid] - d + bbase[blockIdx.x];
        dinv[i] = (d > 0) ? rsqrtf((float)d) : 0.0f;
    }
}

// fill CSR with interleaved (src, weight) pairs -> one 8B load per edge in k_prop
__global__ void k_fill(const int* __restrict__ src, const int* __restrict__ dst,
                       const int* __restrict__ row_start, int* __restrict__ cnt,
                       const float* __restrict__ dinv, int2* __restrict__ csr_sw) {
    int i = blockIdx.x * blockDim.x + threadIdx.x;
    if (i < E_EDGES) {
        int d = dst[i], s = src[i];
        int pos = row_start[d] + atomicAdd(&cnt[d], 1);
        csr_sw[pos] = make_int2(s, __float_as_int(dinv[s] * dinv[d]));
    }
}

// ---------------- fused weight transpose + fp32->bf16 (1 launch) ----------------

__global__ __launch_bounds__(256) void k_cvt_all(const float* __restrict__ wf, const float* __restrict__ wh,
                                                 const float* __restrict__ wv, const float* __restrict__ wt,
                                                 unsigned short* __restrict__ wfT, unsigned short* __restrict__ whT,
                                                 unsigned short* __restrict__ wvT, unsigned short* __restrict__ wtT) {
    int i = blockIdx.x * 256 + threadIdx.x;
    if (i < 49152) {
        int r = i >> 7, c = i & 127;                       // in [384][128]
        wfT[(size_t)c * IN_DIM + r] = f2bf(wf[i]);
    } else if (i < 49152 + 32768) {
        int j = i - 49152;
        int r = j >> 8, c = j & 255;                       // in [128][256]
        whT[(size_t)c * HID + r] = f2bf(wh[j]);
    } else if (i < 49152 + 32768 + 16384) {
        int j = i - 81920;
        int r = j >> 7, c = j & 127;                       // in [128][128]
        wvT[(size_t)c * HID + r] = f2bf(wv[j]);
    } else {
        int j = i - 98304;
        int r = j >> 7, c = j & 127;
        wtT[(size_t)c * HID + r] = f2bf(wt[j]);
    }
}

// ---------------- FUSED: x_emb GEMM (blocks < EMB_NB) || degree count (blocks >= EMB_NB) ----------
// Round-9 post-mortem synthesis: R8 proved high occupancy doubles achieved BW (0.9->1.9 TB/s)
// but its 4x x re-read (FETCH 39->151 MB; per-XCD L2s don't share same-row tiles) swamped it.
// This version keeps BOTH: 4-wave block stages the 16x384 x tile in LDS ONCE (bf16, stride 392
// -> 16B-aligned rows, 2-way-free banks), then each wave computes one 32-col slab from LDS.
// Staging = 6 independent coalesced float4 loads/thread (deep MLP); one barrier; x read 1x.

__global__ __launch_bounds__(256) void k_embdeg(const float* __restrict__ x, const unsigned short* __restrict__ wfT,
                                                const float* __restrict__ bf_, _Float16* __restrict__ x_embh,
                                                const int* __restrict__ dst, int* __restrict__ deg) {
    int b = blockIdx.x;
    int tid = threadIdx.x;
    if (b >= EMB_NB) {
        int i = (b - EMB_NB) * 256 + tid;
        if (i < E_EDGES) atomicAdd(&deg[dst[i]], 1);
        return;
    }
    __shared__ unsigned short xs[16 * XS_STRIDE];  // 12.25 KB
    int m0 = b * 16;
    const float* xbase = x + (size_t)m0 * IN_DIM;
    // stage: 1536 float4 over 256 threads = 6 each, coalesced; convert to bf16 in LDS
#pragma unroll
    for (int pass = 0; pass < 6; ++pass) {
        int j = pass * 256 + tid;            // [0, 1536)
        int row = (j * 683) >> 16;           // j / 96  (exact for j < 6144)
        int col = (j - row * 96) * 4;
        float4 v = *reinterpret_cast<const float4*>(xbase + (size_t)row * IN_DIM + col);
        ushort4 sv = make_ushort4(f2bf(v.x), f2bf(v.y), f2bf(v.z), f2bf(v.w));
        *reinterpret_cast<ushort4*>(&xs[row * XS_STRIDE + col]) = sv;
    }
    __syncthreads();
    int wave = tid >> 6;
    int lane = tid & 63;
    int l16 = lane & 15, quad = lane >> 4;
    int c0 = wave * 32;
    const unsigned short* wp0 = wfT + (size_t)(c0 + l16) * IN_DIM + quad * 8;
    const unsigned short* wp1 = wp0 + (size_t)16 * IN_DIM;
    f32x4 acc0 = (f32x4){0.f, 0.f, 0.f, 0.f};
    f32x4 acc1 = (f32x4){0.f, 0.f, 0.f, 0.f};
#pragma unroll
    for (int kt = 0; kt < 12; ++kt) {
        bf16x8 a = *reinterpret_cast<const bf16x8*>(&xs[l16 * XS_STRIDE + kt * 32 + quad * 8]);
        bf16x8 b0 = *reinterpret_cast<const bf16x8*>(wp0 + kt * 32);
        bf16x8 b1 = *reinterpret_cast<const bf16x8*>(wp1 + kt * 32);
        acc0 = __builtin_amdgcn_mfma_f32_16x16x32_bf16(a, b0, acc0, 0, 0, 0);
        acc1 = __builtin_amdgcn_mfma_f32_16x16x32_bf16(a, b1, acc1, 0, 0, 0);
    }
    float bias0 = bf_[c0 + l16];
    float bias1 = bf_[c0 + 16 + l16];
#pragma unroll
    for (int r = 0; r < 4; ++r) {
        size_t row = (size_t)(m0 + quad * 4 + r);
        x_embh[row * HID + c0 + l16]      = (_Float16)(acc0[r] + bias0);
        x_embh[row * HID + c0 + 16 + l16] = (_Float16)(acc1[r] + bias1);
    }
}

// ---------------- one LightGCN layer: fp16 gather, fp32 accumulate ----------------
// INIT: accb = (float)curh[o] + a   (curh == x_embh)
// else: accb += a.  LAST skips dead nxt store.

__device__ __forceinline__ void fma4h(float4& a, const f16x4 v, float s) {
    a.x = fmaf((float)v.x, s, a.x);
    a.y = fmaf((float)v.y, s, a.y);
    a.z = fmaf((float)v.z, s, a.z);
    a.w = fmaf((float)v.w, s, a.w);
}

template <int INIT, int LAST>
__global__ __launch_bounds__(256) void k_prop(const _Float16* __restrict__ curh, _Float16* __restrict__ nxth,
                                              float* __restrict__ accb,
                                              const int* __restrict__ row_start,
                                              const int2* __restrict__ csr_sw) {
    int tid = threadIdx.x;
    int n = blockIdx.x * 8 + (tid >> 5);
    int c4 = (tid & 31) * 4;
    int s = row_start[n];
    int e = row_start[n + 1];
    float4 a[8];
#pragma unroll
    for (int k = 0; k < 8; ++k) a[k] = (float4){0.f, 0.f, 0.f, 0.f};
    for (int i = s; i < e; i += 8) {
        int2 pk[8];
        float wk[8];
#pragma unroll
        for (int k = 0; k < 8; ++k) {
            int j = i + k;
            pk[k] = csr_sw[(j < e) ? j : s];
            wk[k] = (j < e) ? __int_as_float(pk[k].y) : 0.0f;
        }
        f16x4 v[8];
#pragma unroll
        for (int k = 0; k < 8; ++k)
            v[k] = *reinterpret_cast<const f16x4*>(&curh[(size_t)pk[k].x * HID + c4]);
#pragma unroll
        for (int k = 0; k < 8; ++k) fma4h(a[k], v[k], wk[k]);
    }
    a[0].x += a[1].x; a[0].y += a[1].y; a[0].z += a[1].z; a[0].w += a[1].w;
    a[2].x += a[3].x; a[2].y += a[3].y; a[2].z += a[3].z; a[2].w += a[3].w;
    a[4].x += a[5].x; a[4].y += a[5].y; a[4].z += a[5].z; a[4].w += a[5].w;
    a[6].x += a[7].x; a[6].y += a[7].y; a[6].z += a[7].z; a[6].w += a[7].w;
    a[0].x += a[2].x; a[0].y += a[2].y; a[0].z += a[2].z; a[0].w += a[2].w;
    a[4].x += a[6].x; a[4].y += a[6].y; a[4].z += a[6].z; a[4].w += a[6].w;
    a[0].x += a[4].x; a[0].y += a[4].y; a[0].z += a[4].z; a[0].w += a[4].w;
    size_t o = (size_t)n * HID + c4;
    if (!LAST) {
        f16x4 oh;
        oh.x = (_Float16)a[0].x; oh.y = (_Float16)a[0].y;
        oh.z = (_Float16)a[0].z; oh.w = (_Float16)a[0].w;
        *reinterpret_cast<f16x4*>(&nxth[o]) = oh;
    }
    float4 ac;
    if (INIT) {
        f16x4 bh = *reinterpret_cast<const f16x4*>(&curh[o]);
        ac = make_float4((float)bh.x, (float)bh.y, (float)bh.z, (float)bh.w);
    } else {
        ac = *reinterpret_cast<const float4*>(&accb[o]);
    }
    ac.x += a[0].x; ac.y += a[0].y; ac.z += a[0].z; ac.w += a[0].w;
    *reinterpret_cast<float4*>(&accb[o]) = ac;
}

// ---------------- Hm = softmax((x_emb @ w_hyper + g)/tau) : MFMA, fp16 in/out ----------------

__global__ __launch_bounds__(64) void k_soft(const _Float16* __restrict__ x_embh,
                                             const unsigned short* __restrict__ whT,
                                             const float* __restrict__ gu, _Float16* __restrict__ Hmh) {
    int lane = threadIdx.x & 63;
    int l16 = lane & 15, quad = lane >> 4;
    int m0 = blockIdx.x * 16;
    const _Float16* xrow = x_embh + (size_t)(m0 + l16) * HID + quad * 8;
    f32x4 acc[16];
#pragma unroll
    for (int nt = 0; nt < 16; ++nt) acc[nt] = (f32x4){0.f, 0.f, 0.f, 0.f};
#pragma unroll
    for (int kt = 0; kt < HID / 32; ++kt) {
        f16x8 h = *reinterpret_cast<const f16x8*>(xrow + kt * 32);
        bf16x8 a = cvt8h(h);
#pragma unroll
        for (int nt = 0; nt < 16; ++nt) {
            bf16x8 b = *reinterpret_cast<const bf16x8*>(&whT[(size_t)(nt * 16 + l16) * HID + kt * 32 + quad * 8]);
            acc[nt] = __builtin_amdgcn_mfma_f32_16x16x32_bf16(a, b, acc[nt], 0, 0, 0);
        }
    }
    // gumbel + 1/tau
#pragma unroll
    for (int nt = 0; nt < 16; ++nt) {
        int col = nt * 16 + l16;
#pragma unroll
        for (int r = 0; r < 4; ++r) {
            int row = m0 + quad * 4 + r;
            float u = gu[(size_t)row * HYP + col];
            float g = -logf(-logf(u + 1e-10f) + 1e-10f);
            acc[nt][r] = (acc[nt][r] + g) * 2.0f;
        }
    }
    // row max / sum over cols: per-lane over nt, then shfl over lane&15 group
    float mx[4] = {-3.4e38f, -3.4e38f, -3.4e38f, -3.4e38f};
#pragma unroll
    for (int nt = 0; nt < 16; ++nt)
#pragma unroll
        for (int r = 0; r < 4; ++r) mx[r] = fmaxf(mx[r], acc[nt][r]);
#pragma unroll
    for (int r = 0; r < 4; ++r) {
        mx[r] = fmaxf(mx[r], __shfl_xor(mx[r], 1));
        mx[r] = fmaxf(mx[r], __shfl_xor(mx[r], 2));
        mx[r] = fmaxf(mx[r], __shfl_xor(mx[r], 4));
        mx[r] = fmaxf(mx[r], __shfl_xor(mx[r], 8));
    }
    float sm[4] = {0.f, 0.f, 0.f, 0.f};
#pragma unroll
    for (int nt = 0; nt < 16; ++nt)
#pragma unroll
        for (int r = 0; r < 4; ++r) {
            float e = __expf(acc[nt][r] - mx[r]);
            acc[nt][r] = e;
            sm[r] += e;
        }
#pragma unroll
    for (int r = 0; r < 4; ++r) {
        sm[r] += __shfl_xor(sm[r], 1);
        sm[r] += __shfl_xor(sm[r], 2);
        sm[r] += __shfl_xor(sm[r], 4);
        sm[r] += __shfl_xor(sm[r], 8);
        sm[r] = 1.0f / sm[r];
    }
#pragma unroll
    for (int nt = 0; nt < 16; ++nt) {
        int col = nt * 16 + l16;
#pragma unroll
        for (int r = 0; r < 4; ++r)
            Hmh[(size_t)(m0 + quad * 4 + r) * HYP + col] = (_Float16)(acc[nt][r] * sm[r]);
    }
}

// ---------------- lat = Hm^T @ x_emb : fp16 reads, fp32 outer product, split-K, ATOMIC-FREE ----

#define LAT_KC 384

__global__ __launch_bounds__(256) void k_lat(const _Float16* __restrict__ Hmh, const _Float16* __restrict__ x_embh,
                                             float* __restrict__ part) {
    int htile = blockIdx.x & 1;
    int kc = blockIdx.x >> 1;
    const int chunk = (N_NODES + LAT_KC - 1) / LAT_KC;  // 131
    int start = kc * chunk;
    int end = min(N_NODES, start + chunk);
    int nn = end - start;  // may be <= 0 for the last couple of chunks
    int tid = threadIdx.x;
    int lh = (tid & 15) * 8;               // 8 consecutive h (within half) per thread
    int d = (tid >> 4) * 8;                // 8 consecutive d per thread
    const _Float16* __restrict__ hp = Hmh + (size_t)start * HYP + htile * 128 + lh;
    const _Float16* __restrict__ xp = x_embh + (size_t)start * HID + d;
    float acc[8][8];
#pragma unroll
    for (int i = 0; i < 8; ++i)
#pragma unroll
        for (int j = 0; j < 8; ++j) acc[i][j] = 0.f;
#pragma unroll 2
    for (int n = 0; n < nn; ++n) {
        f16x8 ah = *reinterpret_cast<const f16x8*>(hp);
        f16x8 bh = *reinterpret_cast<const f16x8*>(xp);
        float av[8], bv[8];
#pragma unroll
        for (int i = 0; i < 8; ++i) { av[i] = (float)ah[i]; bv[i] = (float)bh[i]; }
#pragma unroll
        for (int i = 0; i < 8; ++i)
#pragma unroll
            for (int j = 0; j < 8; ++j) acc[i][j] = fmaf(av[i], bv[j], acc[i][j]);
        hp += HYP;
        xp += HID;
    }
    float* __restrict__ pp = part + (size_t)blockIdx.x * (128 * 128) + (size_t)lh * 128 + d;
#pragma unroll
    for (int i = 0; i < 8; ++i) {
        float4 v0 = {acc[i][0], acc[i][1], acc[i][2], acc[i][3]};
        float4 v1 = {acc[i][4], acc[i][5], acc[i][6], acc[i][7]};
        *reinterpret_cast<float4*>(pp + i * 128) = v0;
        *reinterpret_cast<float4*>(pp + i * 128 + 4) = v1;
    }
}

// ---------------- reduce split-K partials -> latT (bf16, transposed) directly ----------------

__global__ __launch_bounds__(256) void k_lat_red(const float* __restrict__ part, unsigned short* __restrict__ latT) {
    int idx = blockIdx.x * 256 + threadIdx.x;  // [0, 32768)
    int d = idx & 127;
    int h = idx >> 7;
    int htile = h >> 7;
    int lh = h & 127;
    const float* __restrict__ p0 = part + (size_t)htile * (128 * 128) + (size_t)lh * 128 + d;
    const size_t kstride = (size_t)2 * 128 * 128;  // consecutive kc
    float s0 = 0.f, s1 = 0.f, s2 = 0.f, s3 = 0.f;
#pragma unroll 4
    for (int k = 0; k < LAT_KC; k += 4) {
        s0 += p0[(size_t)k * kstride];
        s1 += p0[(size_t)(k + 1) * kstride];
        s2 += p0[(size_t)(k + 2) * kstride];
        s3 += p0[(size_t)(k + 3) * kstride];
    }
    latT[(size_t)d * HYP + h] = f2bf((s0 + s1) + (s2 + s3));
}

// ---------------- tail: hyper = Hm @ lat; norm; final; two head GEMMs — MFMA, 1 wave/block ----------------

__global__ __launch_bounds__(64) void k_tail(const _Float16* __restrict__ Hmh, const unsigned short* __restrict__ latT,
                                             const float* __restrict__ accb,
                                             const unsigned short* __restrict__ wvT, const float* __restrict__ bv,
                                             const unsigned short* __restrict__ wtT, const float* __restrict__ bt,
                                             float* __restrict__ out_final, float* __restrict__ out_vis,
                                             float* __restrict__ out_txt) {
    __shared__ unsigned short fl[16 * HID];  // final tile, bf16, 4 KB
    int lane = threadIdx.x & 63;
    int l16 = lane & 15, quad = lane >> 4;
    int m0 = blockIdx.x * 16;
    const _Float16* hrow = Hmh + (size_t)(m0 + l16) * HYP + quad * 8;
    f32x4 acc[8];
#pragma unroll
    for (int nt = 0; nt < 8; ++nt) acc[nt] = (f32x4){0.f, 0.f, 0.f, 0.f};
#pragma unroll
    for (int kt = 0; kt < HYP / 32; ++kt) {
        f16x8 h = *reinterpret_cast<const f16x8*>(hrow + kt * 32);
        bf16x8 a = cvt8h(h);
#pragma unroll
        for (int nt = 0; nt < 8; ++nt) {
            bf16x8 b = *reinterpret_cast<const bf16x8*>(&latT[(size_t)(nt * 16 + l16) * HYP + kt * 32 + quad * 8]);
            acc[nt] = __builtin_amdgcn_mfma_f32_16x16x32_bf16(a, b, acc[nt], 0, 0, 0);
        }
    }
    // per-row L2 norm: rows = m0 + quad*4 + r; reduce over cols = nt x (lane&15)
    float ss[4] = {0.f, 0.f, 0.f, 0.f};
#pragma unroll
    for (int nt = 0; nt < 8; ++nt)
#pragma unroll
        for (int r = 0; r < 4; ++r) ss[r] = fmaf(acc[nt][r], acc[nt][r], ss[r]);
#pragma unroll
    for (int r = 0; r < 4; ++r) {
        ss[r] += __shfl_xor(ss[r], 1);
        ss[r] += __shfl_xor(ss[r], 2);
        ss[r] += __shfl_xor(ss[r], 4);
        ss[r] += __shfl_xor(ss[r], 8);
        ss[r] = 1.0f / fmaxf(sqrtf(ss[r]), 1e-12f);
    }
    // final = accb/4 + 0.1 * normalized; store + stage bf16 tile for head GEMMs
#pragma unroll
    for (int nt = 0; nt < 8; ++nt) {
        int col = nt * 16 + l16;
#pragma unroll
        for (int r = 0; r < 4; ++r) {
            int lrow = quad * 4 + r;
            size_t o = (size_t)(m0 + lrow) * HID + col;
            float f = accb[o] * 0.25f + 0.1f * (acc[nt][r] * ss[r]);
            out_final[o] = f;
            fl[lrow * HID + col] = f2bf(f);
        }
    }
    __syncthreads();
    // heads: A = final tile (LDS), B = wvT / wtT
    f32x4 av[8], at4[8];
#pragma unroll
    for (int nt = 0; nt < 8; ++nt) {
        av[nt] = (f32x4){0.f, 0.f, 0.f, 0.f};
        at4[nt] = (f32x4){0.f, 0.f, 0.f, 0.f};
    }
#pragma unroll
    for (int kt = 0; kt < HID / 32; ++kt) {
        bf16x8 a = *reinterpret_cast<const bf16x8*>(&fl[l16 * HID + kt * 32 + quad * 8]);
#pragma unroll
        for (int nt = 0; nt < 8; ++nt) {
            bf16x8 b1 = *reinterpret_cast<const bf16x8*>(&wvT[(size_t)(nt * 16 + l16) * HID + kt * 32 + quad * 8]);
            bf16x8 b2 = *reinterpret_cast<const bf16x8*>(&wtT[(size_t)(nt * 16 + l16) * HID + kt * 32 + quad * 8]);
            av[nt] = __builtin_amdgcn_mfma_f32_16x16x32_bf16(a, b1, av[nt], 0, 0, 0);
            at4[nt] = __builtin_amdgcn_mfma_f32_16x16x32_bf16(a, b2, at4[nt], 0, 0, 0);
        }
    }
#pragma unroll
    for (int nt = 0; nt < 8; ++nt) {
        int col = nt * 16 + l16;
        float b1 = bv[col], b2 = bt[col];
#pragma unroll
        for (int r = 0; r < 4; ++r) {
            size_t o = (size_t)(m0 + quad * 4 + r) * HID + col;
            out_vis[o] = fmaxf(av[nt][r] + b1, 0.0f);
            out_txt[o] = fmaxf(at4[nt][r] + b2, 0.0f);
        }
    }
}

// ---------------- launch ----------------

extern "C" void kernel_launch(void* const* d_in, const int* in_sizes, int n_in,
                              void* d_out, int out_size, void* d_ws, size_t ws_size,
                              hipStream_t stream) {
    const float* x      = (const float*)d_in[0];
    const int*   ei     = (const int*)d_in[1];
    const float* gu     = (const float*)d_in[2];
    const float* w_feat = (const float*)d_in[3];
    const float* b_feat = (const float*)d_in[4];
    const float* w_hyp  = (const float*)d_in[5];
    const float* w_vis  = (const float*)d_in[6];
    const float* b_vis  = (const float*)d_in[7];
    const float* w_txt  = (const float*)d_in[8];
    const float* b_txt  = (const float*)d_in[9];
    float* out = (float*)d_out;

    const int* srcv = ei;
    const int* dstv = ei + E_EDGES;

    // 64B-aligned workspace carve
    char* p = (char*)d_ws;
    auto carve = [&p](size_t bytes) {
        char* r = p;
        p += (bytes + 63) & ~(size_t)63;
        return r;
    };
    int*      deg     = (int*)carve((size_t)N_NODES * 4);
    int*      cnt     = (int*)carve((size_t)N_NODES * 4);
    int*      rs      = (int*)carve((size_t)(N_NODES + 1) * 4);
    float*    dinv    = (float*)carve((size_t)N_NODES * 4);
    int2*     csr_sw  = (int2*)carve((size_t)E_EDGES * 8);
    _Float16* x_embh  = (_Float16*)carve((size_t)N_NODES * HID * 2);
    float*    bufA    = (float*)carve((size_t)N_NODES * HID * 4);   // fp16 layer bufs + latPart overlay
    float*    bufB    = (float*)carve((size_t)N_NODES * HID * 4);
    float*    accb    = (float*)carve((size_t)N_NODES * HID * 4);
    _Float16* Hmh     = (_Float16*)carve((size_t)N_NODES * HYP * 2);
    unsigned short* wfT  = (unsigned short*)carve((size_t)HID * IN_DIM * 2);
    unsigned short* whT  = (unsigned short*)carve((size_t)HYP * HID * 2);
    unsigned short* wvT  = (unsigned short*)carve((size_t)HID * HID * 2);
    unsigned short* wtT  = (unsigned short*)carve((size_t)HID * HID * 2);
    unsigned short* latT = (unsigned short*)carve((size_t)HID * HYP * 2);
    int*      bsum    = (int*)carve((size_t)SCAN_NB * 4);
    int*      bbase   = (int*)carve((size_t)SCAN_NB * 4);

    // fp16 layer buffers live in the fp32-sized bufA/bufB slots; latPart (768 x 64KB
    // = 50.33 MB split-K partials) overlays bufA+bufB, which are dead after the prop chain.
    _Float16* bufAh = (_Float16*)bufA;
    _Float16* bufBh = (_Float16*)bufB;
    float* latPart = bufA;

    // zero: deg + cnt (first two carves, contiguous)
    (void)hipMemsetAsync(d_ws, 0, (size_t)2 * N_NODES * 4 + 128, stream);

    k_cvt_all<<<448, 256, 0, stream>>>(w_feat, w_hyp, w_vis, w_txt, wfT, whT, wvT, wtT);

    // fused: x_emb GEMM (4-wave LDS-staged 16x128 tiles) || degree count
    k_embdeg<<<EMB_NB + DEG_NB, 256, 0, stream>>>(x, wfT, b_feat, x_embh, dstv, deg);

    k_scan1<<<SCAN_NB, 256, 0, stream>>>(deg, bsum);
    k_scan2<<<1, 256, 0, stream>>>(bsum, bbase, rs);
    k_scan3<<<SCAN_NB, 256, 0, stream>>>(deg, bbase, rs, dinv);
    k_fill<<<(E_EDGES + 255) / 256, 256, 0, stream>>>(srcv, dstv, rs, cnt, dinv, csr_sw);

    k_prop<1, 0><<<N_NODES / 8, 256, 0, stream>>>(x_embh, bufAh, accb, rs, csr_sw);
    k_prop<0, 0><<<N_NODES / 8, 256, 0, stream>>>(bufAh, bufBh, accb, rs, csr_sw);
    k_prop<0, 1><<<N_NODES / 8, 256, 0, stream>>>(bufBh, bufAh, accb, rs, csr_sw);
    k_soft<<<N_NODES / 16, 64, 0, stream>>>(x_embh, whT, gu, Hmh);
    k_lat<<<2 * LAT_KC, 256, 0, stream>>>(Hmh, x_embh, latPart);
    k_lat_red<<<(HYP * HID) / 256, 256, 0, stream>>>(latPart, latT);
    k_tail<<<N_NODES / 16, 64, 0, stream>>>(Hmh, latT, accb, wvT, b_vis, wtT, b_txt,
                                            out, out + (size_t)N_NODES * HID, out + (size_t)2 * N_NODES * HID);
}

// Round 11
// 541.839 us; speedup vs baseline: 1.0687x; 1.0340x over previous
//
#include <hip/hip_runtime.h>
#include <math.h>

#define N_NODES 50000
#define E_EDGES 600000
#define IN_DIM  384
#define HID     128
#define HYP     256

#define SCAN_NB ((N_NODES + 255) / 256)   // 196
#define EMB_NB  (N_NODES / 16)            // 3125: one 16-row tile per 4-wave block
#define DEG_NB  ((E_EDGES + 255) / 256)   // 2344

#define XS_STRIDE 392                     // 384 + 8 bf16 pad (staged x tile)
#define XE_STRIDE 136                     // 128 + 8 bf16 pad (x_emb tile, 16B-aligned rows)

typedef __attribute__((ext_vector_type(8))) short bf16x8;
typedef __attribute__((ext_vector_type(4))) float f32x4;
typedef _Float16 f16x4 __attribute__((ext_vector_type(4)));
typedef _Float16 f16x8 __attribute__((ext_vector_type(8)));

__device__ __forceinline__ unsigned short f2bf(float f) {
    unsigned u = __builtin_bit_cast(unsigned, f);
    u = (u + 0x7FFFu + ((u >> 16) & 1u)) >> 16;
    return (unsigned short)u;
}

__device__ __forceinline__ bf16x8 cvt8(float4 p, float4 q) {
    bf16x8 a;
    a[0] = (short)f2bf(p.x); a[1] = (short)f2bf(p.y);
    a[2] = (short)f2bf(p.z); a[3] = (short)f2bf(p.w);
    a[4] = (short)f2bf(q.x); a[5] = (short)f2bf(q.y);
    a[6] = (short)f2bf(q.z); a[7] = (short)f2bf(q.w);
    return a;
}

// fp16x8 -> bf16x8 via float
__device__ __forceinline__ bf16x8 cvt8h(f16x8 h) {
    bf16x8 a;
#pragma unroll
    for (int i = 0; i < 8; ++i) a[i] = (short)f2bf((float)h[i]);
    return a;
}

// ---------------- graph preprocessing ----------------

__global__ __launch_bounds__(256) void k_scan1(const int* __restrict__ deg, int* __restrict__ bsum) {
    __shared__ int sh[256];
    int tid = threadIdx.x;
    int i = blockIdx.x * 256 + tid;
    sh[tid] = (i < N_NODES) ? deg[i] : 0;
    __syncthreads();
#pragma unroll
    for (int off = 128; off > 0; off >>= 1) {
        if (tid < off) sh[tid] += sh[tid + off];
        __syncthreads();
    }
    if (tid == 0) bsum[blockIdx.x] = sh[0];
}

__global__ __launch_bounds__(256) void k_scan2(const int* __restrict__ bsum, int* __restrict__ bbase,
                                               int* __restrict__ row_start) {
    __shared__ int sh[256];
    int tid = threadIdx.x;
    int v = (tid < SCAN_NB) ? bsum[tid] : 0;
    sh[tid] = v;
    __syncthreads();
#pragma unroll
    for (int off = 1; off < 256; off <<= 1) {
        int t = (tid >= off) ? sh[tid - off] : 0;
        __syncthreads();
        sh[tid] += t;
        __syncthreads();
    }
    if (tid < SCAN_NB) bbase[tid] = sh[tid] - v;  // exclusive prefix of block sums
    if (tid == 0) row_start[N_NODES] = E_EDGES;
}

__global__ __launch_bounds__(256) void k_scan3(const int* __restrict__ deg, const int* __restrict__ bbase,
                                               int* __restrict__ row_start, float* __restrict__ dinv) {
    __shared__ int sh[256];
    int tid = threadIdx.x;
    int i = blockIdx.x * 256 + tid;
    int d = (i < N_NODES) ? deg[i] : 0;
    sh[tid] = d;
    __syncthreads();
#pragma unroll
    for (int off = 1; off < 256; off <<= 1) {
        int t = (tid >= off) ? sh[tid - off] : 0;
        __syncthreads();
        sh[tid] += t;
        __syncthreads();
    }
    if (i < N_NODES) {
        row_start[i] = sh[tid] - d + bbase[blockIdx.x];
        dinv[i] = (d > 0) ? rsqrtf((float)d) : 0.0f;
    }
}

__global__ void k_fill(const int* __restrict__ src, const int* __restrict__ dst,
                       const int* __restrict__ row_start, int* __restrict__ cnt,
                       const float* __restrict__ dinv, int2* __restrict__ csr_sw) {
    int i = blockIdx.x * blockDim.x + threadIdx.x;
    if (i < E_EDGES) {
        int d = dst[i], s = src[i];
        int pos = row_start[d] + atomicAdd(&cnt[d], 1);
        csr_sw[pos] = make_int2(s, __float_as_int(dinv[s] * dinv[d]));
    }
}

// ---------------- fused weight transpose + fp32->bf16 (1 launch) ----------------

__global__ __launch_bounds__(256) void k_cvt_all(const float* __restrict__ wf, const float* __restrict__ wh,
                                                 const float* __restrict__ wv, const float* __restrict__ wt,
                                                 unsigned short* __restrict__ wfT, unsigned short* __restrict__ whT,
                                                 unsigned short* __restrict__ wvT, unsigned short* __restrict__ wtT) {
    int i = blockIdx.x * 256 + threadIdx.x;
    if (i < 49152) {
        int r = i >> 7, c = i & 127;                       // in [384][128]
        wfT[(size_t)c * IN_DIM + r] = f2bf(wf[i]);
    } else if (i < 49152 + 32768) {
        int j = i - 49152;
        int r = j >> 8, c = j & 255;                       // in [128][256]
        whT[(size_t)c * HID + r] = f2bf(wh[j]);
    } else if (i < 49152 + 32768 + 16384) {
        int j = i - 81920;
        int r = j >> 7, c = j & 127;                       // in [128][128]
        wvT[(size_t)c * HID + r] = f2bf(wv[j]);
    } else {
        int j = i - 98304;
        int r = j >> 7, c = j & 127;
        wtT[(size_t)c * HID + r] = f2bf(wt[j]);
    }
}

// ---------------- FUSED: x_emb GEMM + Hm softmax (blocks < EMB_NB) || degree (blocks >= EMB_NB) --
// Round-11 (resubmit of R10; bench infra failed, no kernel signal): k_emb sits at a ~77us floor
// with all pipes <7% busy across 5 structural variants — its idle pipes are free capacity.
// k_soft's entire input (the 16-row x_emb tile) is live in this block at phase-1 end, so soft
// is fused in: phase 2 computes the 16x256 Hm tile from the LDS-resident bf16 x_emb tile
// (4 waves x 64 cols), gumbel from a contiguous 16KB gu slab, and a two-pass softmax (in-wave
// shfl_xor + LDS cross-wave reduce). Deletes the k_soft dispatch and the 12.8MB x_emb re-read.

__global__ __launch_bounds__(256) void k_embdeg(const float* __restrict__ x, const unsigned short* __restrict__ wfT,
                                                const float* __restrict__ bf_, _Float16* __restrict__ x_embh,
                                                const unsigned short* __restrict__ whT, const float* __restrict__ gu,
                                                _Float16* __restrict__ Hmh,
                                                const int* __restrict__ dst, int* __restrict__ deg) {
    int b = blockIdx.x;
    int tid = threadIdx.x;
    if (b >= EMB_NB) {
        int i = (b - EMB_NB) * 256 + tid;
        if (i < E_EDGES) atomicAdd(&deg[dst[i]], 1);
        return;
    }
    __shared__ unsigned short xs[16 * XS_STRIDE];  // 12.25 KB staged x tile (bf16)
    __shared__ unsigned short xe[16 * XE_STRIDE];  // 4.25 KB x_emb tile (bf16)
    __shared__ float wred[16 * 4];                 // cross-wave softmax partials
    int m0 = b * 16;
    const float* xbase = x + (size_t)m0 * IN_DIM;
    // stage: 1536 float4 over 256 threads = 6 each, coalesced; convert to bf16 in LDS
#pragma unroll
    for (int pass = 0; pass < 6; ++pass) {
        int j = pass * 256 + tid;            // [0, 1536)
        int row = (j * 683) >> 16;           // j / 96  (exact for j < 6144)
        int col = (j - row * 96) * 4;
        float4 v = *reinterpret_cast<const float4*>(xbase + (size_t)row * IN_DIM + col);
        ushort4 sv = make_ushort4(f2bf(v.x), f2bf(v.y), f2bf(v.z), f2bf(v.w));
        *reinterpret_cast<ushort4*>(&xs[row * XS_STRIDE + col]) = sv;
    }
    __syncthreads();
    int wave = tid >> 6;
    int lane = tid & 63;
    int l16 = lane & 15, quad = lane >> 4;
    int c0 = wave * 32;
    const unsigned short* wp0 = wfT + (size_t)(c0 + l16) * IN_DIM + quad * 8;
    const unsigned short* wp1 = wp0 + (size_t)16 * IN_DIM;
    f32x4 acc0 = (f32x4){0.f, 0.f, 0.f, 0.f};
    f32x4 acc1 = (f32x4){0.f, 0.f, 0.f, 0.f};
#pragma unroll
    for (int kt = 0; kt < 12; ++kt) {
        bf16x8 a = *reinterpret_cast<const bf16x8*>(&xs[l16 * XS_STRIDE + kt * 32 + quad * 8]);
        bf16x8 b0 = *reinterpret_cast<const bf16x8*>(wp0 + kt * 32);
        bf16x8 b1 = *reinterpret_cast<const bf16x8*>(wp1 + kt * 32);
        acc0 = __builtin_amdgcn_mfma_f32_16x16x32_bf16(a, b0, acc0, 0, 0, 0);
        acc1 = __builtin_amdgcn_mfma_f32_16x16x32_bf16(a, b1, acc1, 0, 0, 0);
    }
    float bias0 = bf_[c0 + l16];
    float bias1 = bf_[c0 + 16 + l16];
#pragma unroll
    for (int r = 0; r < 4; ++r) {
        int lrow = quad * 4 + r;
        size_t row = (size_t)(m0 + lrow);
        float v0 = acc0[r] + bias0;
        float v1 = acc1[r] + bias1;
        x_embh[row * HID + c0 + l16]      = (_Float16)v0;
        x_embh[row * HID + c0 + 16 + l16] = (_Float16)v1;
        xe[lrow * XE_STRIDE + c0 + l16]      = f2bf(v0);
        xe[lrow * XE_STRIDE + c0 + 16 + l16] = f2bf(v1);
    }
    __syncthreads();
    // ---- phase 2: Hm softmax. wave computes cols [wave*64, wave*64+64) = nt 4*wave..4*wave+3
    f32x4 t4[4];
#pragma unroll
    for (int j = 0; j < 4; ++j) t4[j] = (f32x4){0.f, 0.f, 0.f, 0.f};
#pragma unroll
    for (int j = 0; j < 4; ++j) {
        int nt = wave * 4 + j;
        const unsigned short* wh = whT + (size_t)(nt * 16 + l16) * HID + quad * 8;
#pragma unroll
        for (int kt = 0; kt < 4; ++kt) {
            bf16x8 a = *reinterpret_cast<const bf16x8*>(&xe[l16 * XE_STRIDE + kt * 32 + quad * 8]);
            bf16x8 bb = *reinterpret_cast<const bf16x8*>(wh + kt * 32);
            t4[j] = __builtin_amdgcn_mfma_f32_16x16x32_bf16(a, bb, t4[j], 0, 0, 0);
        }
    }
    // gumbel + 1/tau: t = (logit + g) * 2
#pragma unroll
    for (int j = 0; j < 4; ++j) {
        int col = (wave * 4 + j) * 16 + l16;
#pragma unroll
        for (int r = 0; r < 4; ++r) {
            int row = m0 + quad * 4 + r;
            float u = gu[(size_t)row * HYP + col];
            float g = -logf(-logf(u + 1e-10f) + 1e-10f);
            t4[j][r] = (t4[j][r] + g) * 2.0f;
        }
    }
    // pass 1: row max (wave-local over 64 cols, then cross-wave via LDS)
    float mx[4] = {-3.4e38f, -3.4e38f, -3.4e38f, -3.4e38f};
#pragma unroll
    for (int j = 0; j < 4; ++j)
#pragma unroll
        for (int r = 0; r < 4; ++r) mx[r] = fmaxf(mx[r], t4[j][r]);
#pragma unroll
    for (int r = 0; r < 4; ++r) {
        mx[r] = fmaxf(mx[r], __shfl_xor(mx[r], 1));
        mx[r] = fmaxf(mx[r], __shfl_xor(mx[r], 2));
        mx[r] = fmaxf(mx[r], __shfl_xor(mx[r], 4));
        mx[r] = fmaxf(mx[r], __shfl_xor(mx[r], 8));
    }
    if (l16 == 0) {
#pragma unroll
        for (int r = 0; r < 4; ++r) wred[(quad * 4 + r) * 4 + wave] = mx[r];
    }
    __syncthreads();
#pragma unroll
    for (int r = 0; r < 4; ++r) {
        const float* wr = &wred[(quad * 4 + r) * 4];
        mx[r] = fmaxf(fmaxf(wr[0], wr[1]), fmaxf(wr[2], wr[3]));
    }
    __syncthreads();  // wred reads done before sum pass overwrites
    // pass 2: exp + row sum
    float sm[4] = {0.f, 0.f, 0.f, 0.f};
#pragma unroll
    for (int j = 0; j < 4; ++j)
#pragma unroll
        for (int r = 0; r < 4; ++r) {
            float e = __expf(t4[j][r] - mx[r]);
            t4[j][r] = e;
            sm[r] += e;
        }
#pragma unroll
    for (int r = 0; r < 4; ++r) {
        sm[r] += __shfl_xor(sm[r], 1);
        sm[r] += __shfl_xor(sm[r], 2);
        sm[r] += __shfl_xor(sm[r], 4);
        sm[r] += __shfl_xor(sm[r], 8);
    }
    if (l16 == 0) {
#pragma unroll
        for (int r = 0; r < 4; ++r) wred[(quad * 4 + r) * 4 + wave] = sm[r];
    }
    __syncthreads();
#pragma unroll
    for (int r = 0; r < 4; ++r) {
        const float* wr = &wred[(quad * 4 + r) * 4];
        sm[r] = 1.0f / (((wr[0] + wr[1]) + (wr[2] + wr[3])));
    }
#pragma unroll
    for (int j = 0; j < 4; ++j) {
        int col = (wave * 4 + j) * 16 + l16;
#pragma unroll
        for (int r = 0; r < 4; ++r)
            Hmh[(size_t)(m0 + quad * 4 + r) * HYP + col] = (_Float16)(t4[j][r] * sm[r]);
    }
}

// ---------------- one LightGCN layer: fp16 gather, fp32 accumulate ----------------
// INIT: accb = (float)curh[o] + a   (curh == x_embh)
// else: accb += a.  LAST skips dead nxt store.

__device__ __forceinline__ void fma4h(float4& a, const f16x4 v, float s) {
    a.x = fmaf((float)v.x, s, a.x);
    a.y = fmaf((float)v.y, s, a.y);
    a.z = fmaf((float)v.z, s, a.z);
    a.w = fmaf((float)v.w, s, a.w);
}

template <int INIT, int LAST>
__global__ __launch_bounds__(256) void k_prop(const _Float16* __restrict__ curh, _Float16* __restrict__ nxth,
                                              float* __restrict__ accb,
                                              const int* __restrict__ row_start,
                                              const int2* __restrict__ csr_sw) {
    int tid = threadIdx.x;
    int n = blockIdx.x * 8 + (tid >> 5);
    int c4 = (tid & 31) * 4;
    int s = row_start[n];
    int e = row_start[n + 1];
    float4 a[8];
#pragma unroll
    for (int k = 0; k < 8; ++k) a[k] = (float4){0.f, 0.f, 0.f, 0.f};
    for (int i = s; i < e; i += 8) {
        int2 pk[8];
        float wk[8];
#pragma unroll
        for (int k = 0; k < 8; ++k) {
            int j = i + k;
            pk[k] = csr_sw[(j < e) ? j : s];
            wk[k] = (j < e) ? __int_as_float(pk[k].y) : 0.0f;
        }
        f16x4 v[8];
#pragma unroll
        for (int k = 0; k < 8; ++k)
            v[k] = *reinterpret_cast<const f16x4*>(&curh[(size_t)pk[k].x * HID + c4]);
#pragma unroll
        for (int k = 0; k < 8; ++k) fma4h(a[k], v[k], wk[k]);
    }
    a[0].x += a[1].x; a[0].y += a[1].y; a[0].z += a[1].z; a[0].w += a[1].w;
    a[2].x += a[3].x; a[2].y += a[3].y; a[2].z += a[3].z; a[2].w += a[3].w;
    a[4].x += a[5].x; a[4].y += a[5].y; a[4].z += a[5].z; a[4].w += a[5].w;
    a[6].x += a[7].x; a[6].y += a[7].y; a[6].z += a[7].z; a[6].w += a[7].w;
    a[0].x += a[2].x; a[0].y += a[2].y; a[0].z += a[2].z; a[0].w += a[2].w;
    a[4].x += a[6].x; a[4].y += a[6].y; a[4].z += a[6].z; a[4].w += a[6].w;
    a[0].x += a[4].x; a[0].y += a[4].y; a[0].z += a[4].z; a[0].w += a[4].w;
    size_t o = (size_t)n * HID + c4;
    if (!LAST) {
        f16x4 oh;
        oh.x = (_Float16)a[0].x; oh.y = (_Float16)a[0].y;
        oh.z = (_Float16)a[0].z; oh.w = (_Float16)a[0].w;
        *reinterpret_cast<f16x4*>(&nxth[o]) = oh;
    }
    float4 ac;
    if (INIT) {
        f16x4 bh = *reinterpret_cast<const f16x4*>(&curh[o]);
        ac = make_float4((float)bh.x, (float)bh.y, (float)bh.z, (float)bh.w);
    } else {
        ac = *reinterpret_cast<const float4*>(&accb[o]);
    }
    ac.x += a[0].x; ac.y += a[0].y; ac.z += a[0].z; ac.w += a[0].w;
    *reinterpret_cast<float4*>(&accb[o]) = ac;
}

// ---------------- lat = Hm^T @ x_emb : fp16 reads, fp32 outer product, split-K, ATOMIC-FREE ----

#define LAT_KC 384

__global__ __launch_bounds__(256) void k_lat(const _Float16* __restrict__ Hmh, const _Float16* __restrict__ x_embh,
                                             float* __restrict__ part) {
    int htile = blockIdx.x & 1;
    int kc = blockIdx.x >> 1;
    const int chunk = (N_NODES + LAT_KC - 1) / LAT_KC;  // 131
    int start = kc * chunk;
    int end = min(N_NODES, start + chunk);
    int nn = end - start;  // may be <= 0 for the last couple of chunks
    int tid = threadIdx.x;
    int lh = (tid & 15) * 8;               // 8 consecutive h (within half) per thread
    int d = (tid >> 4) * 8;                // 8 consecutive d per thread
    const _Float16* __restrict__ hp = Hmh + (size_t)start * HYP + htile * 128 + lh;
    const _Float16* __restrict__ xp = x_embh + (size_t)start * HID + d;
    float acc[8][8];
#pragma unroll
    for (int i = 0; i < 8; ++i)
#pragma unroll
        for (int j = 0; j < 8; ++j) acc[i][j] = 0.f;
#pragma unroll 2
    for (int n = 0; n < nn; ++n) {
        f16x8 ah = *reinterpret_cast<const f16x8*>(hp);
        f16x8 bh = *reinterpret_cast<const f16x8*>(xp);
        float av[8], bv[8];
#pragma unroll
        for (int i = 0; i < 8; ++i) { av[i] = (float)ah[i]; bv[i] = (float)bh[i]; }
#pragma unroll
        for (int i = 0; i < 8; ++i)
#pragma unroll
            for (int j = 0; j < 8; ++j) acc[i][j] = fmaf(av[i], bv[j], acc[i][j]);
        hp += HYP;
        xp += HID;
    }
    float* __restrict__ pp = part + (size_t)blockIdx.x * (128 * 128) + (size_t)lh * 128 + d;
#pragma unroll
    for (int i = 0; i < 8; ++i) {
        float4 v0 = {acc[i][0], acc[i][1], acc[i][2], acc[i][3]};
        float4 v1 = {acc[i][4], acc[i][5], acc[i][6], acc[i][7]};
        *reinterpret_cast<float4*>(pp + i * 128) = v0;
        *reinterpret_cast<float4*>(pp + i * 128 + 4) = v1;
    }
}

// ---------------- reduce split-K partials -> latT (bf16, transposed) directly ----------------

__global__ __launch_bounds__(256) void k_lat_red(const float* __restrict__ part, unsigned short* __restrict__ latT) {
    int idx = blockIdx.x * 256 + threadIdx.x;  // [0, 32768)
    int d = idx & 127;
    int h = idx >> 7;
    int htile = h >> 7;
    int lh = h & 127;
    const float* __restrict__ p0 = part + (size_t)htile * (128 * 128) + (size_t)lh * 128 + d;
    const size_t kstride = (size_t)2 * 128 * 128;  // consecutive kc
    float s0 = 0.f, s1 = 0.f, s2 = 0.f, s3 = 0.f;
#pragma unroll 4
    for (int k = 0; k < LAT_KC; k += 4) {
        s0 += p0[(size_t)k * kstride];
        s1 += p0[(size_t)(k + 1) * kstride];
        s2 += p0[(size_t)(k + 2) * kstride];
        s3 += p0[(size_t)(k + 3) * kstride];
    }
    latT[(size_t)d * HYP + h] = f2bf((s0 + s1) + (s2 + s3));
}

// ---------------- tail: hyper = Hm @ lat; norm; final; two head GEMMs — MFMA, 1 wave/block ----------------

__global__ __launch_bounds__(64) void k_tail(const _Float16* __restrict__ Hmh, const unsigned short* __restrict__ latT,
                                             const float* __restrict__ accb,
                                             const unsigned short* __restrict__ wvT, const float* __restrict__ bv,
                                             const unsigned short* __restrict__ wtT, const float* __restrict__ bt,
                                             float* __restrict__ out_final, float* __restrict__ out_vis,
                                             float* __restrict__ out_txt) {
    __shared__ unsigned short fl[16 * HID];  // final tile, bf16, 4 KB
    int lane = threadIdx.x & 63;
    int l16 = lane & 15, quad = lane >> 4;
    int m0 = blockIdx.x * 16;
    const _Float16* hrow = Hmh + (size_t)(m0 + l16) * HYP + quad * 8;
    f32x4 acc[8];
#pragma unroll
    for (int nt = 0; nt < 8; ++nt) acc[nt] = (f32x4){0.f, 0.f, 0.f, 0.f};
#pragma unroll
    for (int kt = 0; kt < HYP / 32; ++kt) {
        f16x8 h = *reinterpret_cast<const f16x8*>(hrow + kt * 32);
        bf16x8 a = cvt8h(h);
#pragma unroll
        for (int nt = 0; nt < 8; ++nt) {
            bf16x8 b = *reinterpret_cast<const bf16x8*>(&latT[(size_t)(nt * 16 + l16) * HYP + kt * 32 + quad * 8]);
            acc[nt] = __builtin_amdgcn_mfma_f32_16x16x32_bf16(a, b, acc[nt], 0, 0, 0);
        }
    }
    // per-row L2 norm: rows = m0 + quad*4 + r; reduce over cols = nt x (lane&15)
    float ss[4] = {0.f, 0.f, 0.f, 0.f};
#pragma unroll
    for (int nt = 0; nt < 8; ++nt)
#pragma unroll
        for (int r = 0; r < 4; ++r) ss[r] = fmaf(acc[nt][r], acc[nt][r], ss[r]);
#pragma unroll
    for (int r = 0; r < 4; ++r) {
        ss[r] += __shfl_xor(ss[r], 1);
        ss[r] += __shfl_xor(ss[r], 2);
        ss[r] += __shfl_xor(ss[r], 4);
        ss[r] += __shfl_xor(ss[r], 8);
        ss[r] = 1.0f / fmaxf(sqrtf(ss[r]), 1e-12f);
    }
    // final = accb/4 + 0.1 * normalized; store + stage bf16 tile for head GEMMs
#pragma unroll
    for (int nt = 0; nt < 8; ++nt) {
        int col = nt * 16 + l16;
#pragma unroll
        for (int r = 0; r < 4; ++r) {
            int lrow = quad * 4 + r;
            size_t o = (size_t)(m0 + lrow) * HID + col;
            float f = accb[o] * 0.25f + 0.1f * (acc[nt][r] * ss[r]);
            out_final[o] = f;
            fl[lrow * HID + col] = f2bf(f);
        }
    }
    __syncthreads();
    // heads: A = final tile (LDS), B = wvT / wtT
    f32x4 av[8], at4[8];
#pragma unroll
    for (int nt = 0; nt < 8; ++nt) {
        av[nt] = (f32x4){0.f, 0.f, 0.f, 0.f};
        at4[nt] = (f32x4){0.f, 0.f, 0.f, 0.f};
    }
#pragma unroll
    for (int kt = 0; kt < HID / 32; ++kt) {
        bf16x8 a = *reinterpret_cast<const bf16x8*>(&fl[l16 * HID + kt * 32 + quad * 8]);
#pragma unroll
        for (int nt = 0; nt < 8; ++nt) {
            bf16x8 b1 = *reinterpret_cast<const bf16x8*>(&wvT[(size_t)(nt * 16 + l16) * HID + kt * 32 + quad * 8]);
            bf16x8 b2 = *reinterpret_cast<const bf16x8*>(&wtT[(size_t)(nt * 16 + l16) * HID + kt * 32 + quad * 8]);
            av[nt] = __builtin_amdgcn_mfma_f32_16x16x32_bf16(a, b1, av[nt], 0, 0, 0);
            at4[nt] = __builtin_amdgcn_mfma_f32_16x16x32_bf16(a, b2, at4[nt], 0, 0, 0);
        }
    }
#pragma unroll
    for (int nt = 0; nt < 8; ++nt) {
        int col = nt * 16 + l16;
        float b1 = bv[col], b2 = bt[col];
#pragma unroll
        for (int r = 0; r < 4; ++r) {
            size_t o = (size_t)(m0 + quad * 4 + r) * HID + col;
            out_vis[o] = fmaxf(av[nt][r] + b1, 0.0f);
            out_txt[o] = fmaxf(at4[nt][r] + b2, 0.0f);
        }
    }
}

// ---------------- launch ----------------

extern "C" void kernel_launch(void* const* d_in, const int* in_sizes, int n_in,
                              void* d_out, int out_size, void* d_ws, size_t ws_size,
                              hipStream_t stream) {
    const float* x      = (const float*)d_in[0];
    const int*   ei     = (const int*)d_in[1];
    const float* gu     = (const float*)d_in[2];
    const float* w_feat = (const float*)d_in[3];
    const float* b_feat = (const float*)d_in[4];
    const float* w_hyp  = (const float*)d_in[5];
    const float* w_vis  = (const float*)d_in[6];
    const float* b_vis  = (const float*)d_in[7];
    const float* w_txt  = (const float*)d_in[8];
    const float* b_txt  = (const float*)d_in[9];
    float* out = (float*)d_out;

    const int* srcv = ei;
    const int* dstv = ei + E_EDGES;

    // 64B-aligned workspace carve
    char* p = (char*)d_ws;
    auto carve = [&p](size_t bytes) {
        char* r = p;
        p += (bytes + 63) & ~(size_t)63;
        return r;
    };
    int*      deg     = (int*)carve((size_t)N_NODES * 4);
    int*      cnt     = (int*)carve((size_t)N_NODES * 4);
    int*      rs      = (int*)carve((size_t)(N_NODES + 1) * 4);
    float*    dinv    = (float*)carve((size_t)N_NODES * 4);
    int2*     csr_sw  = (int2*)carve((size_t)E_EDGES * 8);
    _Float16* x_embh  = (_Float16*)carve((size_t)N_NODES * HID * 2);
    float*    bufA    = (float*)carve((size_t)N_NODES * HID * 4);   // fp16 layer bufs + latPart overlay
    float*    bufB    = (float*)carve((size_t)N_NODES * HID * 4);
    float*    accb    = (float*)carve((size_t)N_NODES * HID * 4);
    _Float16* Hmh     = (_Float16*)carve((size_t)N_NODES * HYP * 2);
    unsigned short* wfT  = (unsigned short*)carve((size_t)HID * IN_DIM * 2);
    unsigned short* whT  = (unsigned short*)carve((size_t)HYP * HID * 2);
    unsigned short* wvT  = (unsigned short*)carve((size_t)HID * HID * 2);
    unsigned short* wtT  = (unsigned short*)carve((size_t)HID * HID * 2);
    unsigned short* latT = (unsigned short*)carve((size_t)HID * HYP * 2);
    int*      bsum    = (int*)carve((size_t)SCAN_NB * 4);
    int*      bbase   = (int*)carve((size_t)SCAN_NB * 4);

    // fp16 layer buffers live in the fp32-sized bufA/bufB slots; latPart (768 x 64KB
    // = 50.33 MB split-K partials) overlays bufA+bufB, which are dead after the prop chain.
    _Float16* bufAh = (_Float16*)bufA;
    _Float16* bufBh = (_Float16*)bufB;
    float* latPart = bufA;

    // zero: deg + cnt (first two carves, contiguous)
    (void)hipMemsetAsync(d_ws, 0, (size_t)2 * N_NODES * 4 + 128, stream);

    k_cvt_all<<<448, 256, 0, stream>>>(w_feat, w_hyp, w_vis, w_txt, wfT, whT, wvT, wtT);

    // fused: x_emb GEMM + Hm softmax (4-wave LDS-staged tiles) || degree count
    k_embdeg<<<EMB_NB + DEG_NB, 256, 0, stream>>>(x, wfT, b_feat, x_embh, whT, gu, Hmh, dstv, deg);

    k_scan1<<<SCAN_NB, 256, 0, stream>>>(deg, bsum);
    k_scan2<<<1, 256, 0, stream>>>(bsum, bbase, rs);
    k_scan3<<<SCAN_NB, 256, 0, stream>>>(deg, bbase, rs, dinv);
    k_fill<<<(E_EDGES + 255) / 256, 256, 0, stream>>>(srcv, dstv, rs, cnt, dinv, csr_sw);

    k_prop<1, 0><<<N_NODES / 8, 256, 0, stream>>>(x_embh, bufAh, accb, rs, csr_sw);
    k_prop<0, 0><<<N_NODES / 8, 256, 0, stream>>>(bufAh, bufBh, accb, rs, csr_sw);
    k_prop<0, 1><<<N_NODES / 8, 256, 0, stream>>>(bufBh, bufAh, accb, rs, csr_sw);
    k_lat<<<2 * LAT_KC, 256, 0, stream>>>(Hmh, x_embh, latPart);
    k_lat_red<<<(HYP * HID) / 256, 256, 0, stream>>>(latPart, latT);
    k_tail<<<N_NODES / 16, 64, 0, stream>>>(Hmh, latT, accb, wvT, b_vis, wtT, b_txt,
                                            out, out + (size_t)N_NODES * HID, out + (size_t)2 * N_NODES * HID);
}